// Round 3
// baseline (718.167 us; speedup 1.0000x reference)
//
#include <hip/hip_runtime.h>

#define NB    4
#define NPTS  4096
#define DF    32      // D*C
#define DD    4
#define CC    8
#define CO    16
#define KNN   16
#define TILE  64      // candidates per LDS tile
#define RPW   2       // rows per wave (two independent full-wave top-64 lists)
#define WPB   4       // waves per block
#define RPB   (RPW*WPB)

__device__ __forceinline__ unsigned int sortable32(float f) {
    unsigned int u = __float_as_uint(f);
    return (u & 0x80000000u) ? ~u : (u | 0x80000000u);
}

// Full-wave sorted top-64 insert: `run` is sorted ascending across the 64
// lanes of the wave (lane 0 = best). Monotone: run[i] only ever decreases.
__device__ __forceinline__ void insert64(unsigned long long& run,
                                         unsigned long long key, int lane) {
    unsigned long long T = __shfl(run, 63);          // current worst
    unsigned long long bal = __ballot(key < T);
    while (bal) {
        int src = __builtin_ctzll(bal);
        bal &= bal - 1;
        unsigned long long kk = __shfl(key, src);
        if (kk < T) {                                // wave-uniform re-test
            unsigned long long prev = __shfl_up(run, 1);
            bool kb  = kk < run;
            bool kbp = (lane != 0) && (kk < prev);
            run = kb ? (kbp ? prev : kk) : run;      // sorted shift-insert
            T = __shfl(run, 63);
        }
    }
}

__global__ __launch_bounds__(256)
void wfm_kernel(const float* __restrict__ x, const float* __restrict__ w1,
                const float* __restrict__ w2, float* __restrict__ out) {
    const int tid  = threadIdx.x;
    const int lane = tid & 63;
    const int wave = tid >> 6;
    const int b    = blockIdx.x / (NPTS / RPB);
    const int rblk = blockIdx.x % (NPTS / RPB);
    const int n0   = rblk * RPB + wave * RPW;

    const float*  xb  = x + (size_t)b * NPTS * DF;
    const float4* xb4 = (const float4*)xb;

    __shared__ float4 tileT[8 * TILE];   // [f4][cand ^ f4] swizzled transpose
    __shared__ float  w1n[CC][KNN];
    __shared__ float  w2n[CC][CO];
    __shared__ float  nrm[CC + CO];

    // ---- normalize weights (w1 rows over K, w2 cols over C) ----
    if (tid < CC) {
        float s = 0.f;
        for (int k = 0; k < KNN; ++k) { float v = w1[tid * KNN + k]; s = fmaf(v, v, s); }
        nrm[tid] = sqrtf(s);
    } else if (tid < CC + CO) {
        int o = tid - CC; float s = 0.f;
        for (int c = 0; c < CC; ++c) { float v = w2[c * CO + o]; s = fmaf(v, v, s); }
        nrm[tid] = sqrtf(s);
    }
    __syncthreads();
    if (tid < CC * KNN) w1n[tid >> 4][tid & 15] = w1[tid] / nrm[tid >> 4];
    if (tid < CC * CO)  w2n[tid >> 4][tid & 15] = w2[tid] / nrm[CC + (tid & 15)];

    // ---- row features (2 rows per wave, kept in registers) ----
    float rf[RPW][DF];
#pragma unroll
    for (int r = 0; r < RPW; ++r)
#pragma unroll
        for (int f = 0; f < DF; ++f)
            rf[r][f] = xb[(size_t)(n0 + r) * DF + f];

    // ---- fp32 scan: two full-wave sorted top-64 lists (superset of top-16) ----
    unsigned long long run0 = ~0ull, run1 = ~0ull;

    for (int t = 0; t < NPTS; t += TILE) {
        __syncthreads();
#pragma unroll
        for (int p = 0; p < 2; ++p) {
            int idx = p * 256 + tid;
            int cand = idx >> 3, f4 = idx & 7;
            tileT[f4 * TILE + (cand ^ f4)] = xb4[(size_t)t * 8 + idx];
        }
        __syncthreads();

        const int m = t + lane;
        float sq = 0.f, dot0 = 0.f, dot1 = 0.f;
#pragma unroll
        for (int f4 = 0; f4 < 8; ++f4) {
            float4 v = tileT[f4 * TILE + (lane ^ f4)];   // conflict-free b128
            sq   = fmaf(v.x, v.x, sq);
            sq   = fmaf(v.y, v.y, sq);
            sq   = fmaf(v.z, v.z, sq);
            sq   = fmaf(v.w, v.w, sq);
            dot0 = fmaf(v.x, rf[0][f4*4+0], dot0);
            dot0 = fmaf(v.y, rf[0][f4*4+1], dot0);
            dot0 = fmaf(v.z, rf[0][f4*4+2], dot0);
            dot0 = fmaf(v.w, rf[0][f4*4+3], dot0);
            dot1 = fmaf(v.x, rf[1][f4*4+0], dot1);
            dot1 = fmaf(v.y, rf[1][f4*4+1], dot1);
            dot1 = fmaf(v.z, rf[1][f4*4+2], dot1);
            dot1 = fmaf(v.w, rf[1][f4*4+3], dot1);
        }
        float d0 = sq - 2.0f * dot0;
        float d1 = sq - 2.0f * dot1;
        unsigned long long key0 =
            ((unsigned long long)sortable32(d0) << 32) | (unsigned)m;
        unsigned long long key1 =
            ((unsigned long long)sortable32(d1) << 32) | (unsigned)m;
        insert64(run0, key0, lane);
        insert64(run1, key1, lane);
    }

    // ---- per row: canonical-fp32 re-rank of 64 survivors + output ----
    // dist32 = fl32( fl32(sq32[n] + sq32[m]) - fl32(2 * dot32) ), components
    // correctly rounded via fp64 accumulation (exact 24x24-bit products).
    // Ties in dist32 break by LOWER index — jax.lax.top_k semantics.
#pragma unroll
    for (int rr = 0; rr < RPW; ++rr) {
        unsigned long long run = (rr == 0) ? run0 : run1;
        int mym = (int)(run & 0xFFFFFFFFull);

        double dot64 = 0.0, sqm64 = 0.0, sqn64 = 0.0;
        const float* cp = xb + (size_t)mym * DF;
#pragma unroll
        for (int f = 0; f < DF; ++f) {
            double cv = (double)cp[f];
            double rv = (double)rf[rr][f];      // rr static after unroll
            dot64 = fma(rv, cv, dot64);
            sqm64 = fma(cv, cv, sqm64);
            sqn64 = fma(rv, rv, sqn64);
        }
        float sqn32  = (float)sqn64;
        float sqm32  = (float)sqm64;
        float dot32  = (float)dot64;
        float dist32 = (sqn32 + sqm32) - 2.0f * dot32;

        unsigned long long key =
            ((unsigned long long)sortable32(dist32) << 32) | (unsigned)mym;

        // full-wave bitonic sort, ascending on (dist32, index)
#pragma unroll
        for (int k = 2; k <= 64; k <<= 1) {
#pragma unroll
            for (int j = k >> 1; j > 0; j >>= 1) {
                unsigned long long ok = __shfl_xor(key, j);
                bool up       = ((lane & k) == 0);
                bool lower    = ((lane & j) == 0);
                bool takeMin  = (lower == up);
                bool mineLess = (key < ok);
                if (takeMin != mineLess) key = ok;
            }
        }
        mym = (int)(key & 0xFFFFFFFFull);
        // lane k (k<16) now holds the rank-k neighbor index

        const int nn = n0 + rr;
        float wsum = 0.f;
#pragma unroll
        for (int k = 0; k < KNN; ++k) {
            int mk = __shfl(mym, k);                       // uniform
            float v = 0.f;
            if (lane < DF) v = xb[(size_t)mk * DF + lane]; // coalesced gather
            wsum = fmaf(v, w1n[lane & 7][k], wsum);        // lane = d*8+c
        }
        float ov = 0.f;
        const int d_ = lane >> 4, o_ = lane & 15;
#pragma unroll
        for (int c = 0; c < CC; ++c) {
            float wv = __shfl(wsum, d_ * CC + c);
            ov = fmaf(wv, w2n[c][o_], ov);
        }
        out[(size_t)(b * NPTS + nn) * (DD * CO) + lane] = ov;
    }
}

extern "C" void kernel_launch(void* const* d_in, const int* in_sizes, int n_in,
                              void* d_out, int out_size, void* d_ws, size_t ws_size,
                              hipStream_t stream) {
    const float* x  = (const float*)d_in[0];
    const float* w1 = (const float*)d_in[1];
    const float* w2 = (const float*)d_in[2];
    float* out = (float*)d_out;

    wfm_kernel<<<NB * (NPTS / RPB), 256, 0, stream>>>(x, w1, w2, out);
}

// Round 4
// 421.385 us; speedup vs baseline: 1.7043x; 1.7043x over previous
//
#include <hip/hip_runtime.h>

#define NB    4
#define NPTS  4096
#define DF    32      // D*C
#define DD    4
#define CC    8
#define CO    16
#define KNN   16
#define TILE  128     // candidates per LDS tile
#define RPW   2       // rows per wave
#define WPB   4       // waves per block
#define RPB   (RPW*WPB)
#define FIFO_N 128    // per-row pending-candidate ring (max pending 63+64=127)

__device__ __forceinline__ unsigned sortable32(float f) {
    unsigned u = __float_as_uint(f);
    return (u & 0x80000000u) ? ~u : (u | 0x80000000u);
}
__device__ __forceinline__ unsigned long long sortable64(double f) {
    unsigned long long u = (unsigned long long)__double_as_longlong(f);
    return (u & 0x8000000000000000ull) ? ~u : (u | 0x8000000000000000ull);
}

// Full-wave ascending bitonic sort of one u32 per lane (verified network, R3).
__device__ __forceinline__ unsigned bitonic_sort64(unsigned key, int lane) {
#pragma unroll
    for (int k = 2; k <= 64; k <<= 1) {
#pragma unroll
        for (int j = k >> 1; j > 0; j >>= 1) {
            unsigned o = __shfl_xor(key, j);
            bool up       = ((lane & k) == 0);
            bool lower    = ((lane & j) == 0);
            bool takeMin  = (lower == up);
            bool mineLess = key < o;
            if (takeMin != mineLess) key = o;
        }
    }
    return key;
}
// Sort a bitonic 64-sequence ascending (cleanup half of a bitonic merge).
__device__ __forceinline__ unsigned bitonic_clean64(unsigned v, int lane) {
#pragma unroll
    for (int j = 32; j > 0; j >>= 1) {
        unsigned o = __shfl_xor(v, j);
        bool lower = ((lane & j) == 0);
        v = lower ? min(v, o) : max(v, o);
    }
    return v;
}
// Merge an unsorted batch (1 key/lane) into sorted-ascending run (1 key/lane),
// keeping the smallest 64 of the 128. Batcher: sort batch, reverse, min, clean.
__device__ __forceinline__ void merge_batch(unsigned& run, unsigned bk, int lane) {
    bk = bitonic_sort64(bk, lane);
    unsigned rev = __shfl(bk, 63 - lane);      // descending copy of batch
    unsigned lo  = min(run, rev);              // lower half = smallest 64 (bitonic)
    run = bitonic_clean64(lo, lane);
}

__global__ __launch_bounds__(256)
void wfm_kernel(const float* __restrict__ x, const float* __restrict__ w1,
                const float* __restrict__ w2, float* __restrict__ out) {
    const int tid  = threadIdx.x;
    const int lane = tid & 63;
    const int wave = tid >> 6;
    const int b    = blockIdx.x / (NPTS / RPB);
    const int rblk = blockIdx.x % (NPTS / RPB);
    const int n0   = rblk * RPB + wave * RPW;

    const float*  xb  = x + (size_t)b * NPTS * DF;
    const float4* xb4 = (const float4*)xb;

    __shared__ float4  tileT[8 * TILE];           // [f4][cand ^ f4] swizzled
    __shared__ unsigned fifo[WPB][RPW][FIFO_N];   // pending-candidate rings
    __shared__ float   w1n[CC][KNN];
    __shared__ float   w2n[CC][CO];
    __shared__ float   nrm[CC + CO];

    // ---- normalize weights (w1 rows over K, w2 cols over C) ----
    if (tid < CC) {
        float s = 0.f;
        for (int k = 0; k < KNN; ++k) { float v = w1[tid * KNN + k]; s = fmaf(v, v, s); }
        nrm[tid] = sqrtf(s);
    } else if (tid < CC + CO) {
        int o = tid - CC; float s = 0.f;
        for (int c = 0; c < CC; ++c) { float v = w2[c * CO + o]; s = fmaf(v, v, s); }
        nrm[tid] = sqrtf(s);
    }
    __syncthreads();
    if (tid < CC * KNN) w1n[tid >> 4][tid & 15] = w1[tid] / nrm[tid >> 4];
    if (tid < CC * CO)  w2n[tid >> 4][tid & 15] = w2[tid] / nrm[CC + (tid & 15)];

    // ---- row features (2 rows per wave, kept in registers) ----
    float rf[RPW][DF];
#pragma unroll
    for (int r = 0; r < RPW; ++r)
#pragma unroll
        for (int f = 0; f < DF; ++f)
            rf[r][f] = xb[(size_t)(n0 + r) * DF + f];

    // ---- scan state: sorted top-64 run + lazy threshold + FIFO bookkeeping ----
    unsigned run0 = 0xFFFFFFFFu, run1 = 0xFFFFFFFFu;
    unsigned T0 = 0xFFFFFFFFu,   T1 = 0xFFFFFFFFu;
    int base0 = 0, cnt0 = 0, base1 = 0, cnt1 = 0;
    unsigned* ff0 = &fifo[wave][0][0];
    unsigned* ff1 = &fifo[wave][1][0];

    auto accept = [&](unsigned key, unsigned& run, unsigned& T,
                      int& base, int& cnt, unsigned* ff) {
        bool acc = key < T;
        unsigned long long bal = __ballot(acc);
        if (bal) {                                   // wave-uniform
            int pos = cnt + (int)__popcll(bal & ((1ull << lane) - 1ull));
            if (acc) ff[(base + pos) & (FIFO_N - 1)] = key;
            cnt += (int)__popcll(bal);
            __builtin_amdgcn_wave_barrier();         // order fifo write vs read
            asm volatile("" ::: "memory");
            while (cnt >= 64) {                      // wave-uniform
                unsigned bk = ff[(base + lane) & (FIFO_N - 1)];
                base += 64; cnt -= 64;
                merge_batch(run, bk, lane);
                T = __shfl(run, 63);
            }
        }
    };

    // ---- tiled scan with register prefetch of the next tile ----
    float4 pf[4];
#pragma unroll
    for (int q = 0; q < 4; ++q) pf[q] = xb4[q * 256 + tid];   // tile 0

#pragma unroll 1
    for (int t = 0; t < NPTS; t += TILE) {
        __syncthreads();                       // previous tile's consumers done
#pragma unroll
        for (int q = 0; q < 4; ++q) {
            int idx = q * 256 + tid;
            int cand = idx >> 3, f4 = idx & 7;
            tileT[f4 * TILE + (cand ^ f4)] = pf[q];
        }
        __syncthreads();                       // tile t visible
        int tn = (t + TILE < NPTS) ? (t + TILE) : 0;   // harmless wrap reload
#pragma unroll
        for (int q = 0; q < 4; ++q)
            pf[q] = xb4[(size_t)tn * 8 + q * 256 + tid];   // hidden under compute

#pragma unroll
        for (int p = 0; p < 2; ++p) {
            const int c = p * 64 + lane;
            float sq = 0.f, dot0 = 0.f, dot1 = 0.f;
#pragma unroll
            for (int f4 = 0; f4 < 8; ++f4) {
                float4 v = tileT[f4 * TILE + (c ^ f4)];    // conflict-free b128
                sq   = fmaf(v.x, v.x, sq);
                sq   = fmaf(v.y, v.y, sq);
                sq   = fmaf(v.z, v.z, sq);
                sq   = fmaf(v.w, v.w, sq);
                dot0 = fmaf(v.x, rf[0][f4*4+0], dot0);
                dot0 = fmaf(v.y, rf[0][f4*4+1], dot0);
                dot0 = fmaf(v.z, rf[0][f4*4+2], dot0);
                dot0 = fmaf(v.w, rf[0][f4*4+3], dot0);
                dot1 = fmaf(v.x, rf[1][f4*4+0], dot1);
                dot1 = fmaf(v.y, rf[1][f4*4+1], dot1);
                dot1 = fmaf(v.z, rf[1][f4*4+2], dot1);
                dot1 = fmaf(v.w, rf[1][f4*4+3], dot1);
            }
            float d0 = fmaf(-2.f, dot0, sq);   // sq_n const per row: order-free
            float d1 = fmaf(-2.f, dot1, sq);
            unsigned m = (unsigned)(t + c);
            unsigned key0 = (sortable32(d0) & 0xFFFFF000u) | m;
            unsigned key1 = (sortable32(d1) & 0xFFFFF000u) | m;
            accept(key0, run0, T0, base0, cnt0, ff0);
            accept(key1, run1, T1, base1, cnt1, ff1);
        }
    }

    // ---- drain pending FIFOs (pad with +inf keys) ----
    if (cnt0 > 0) {
        unsigned bk = (lane < cnt0) ? ff0[(base0 + lane) & (FIFO_N - 1)] : 0xFFFFFFFFu;
        merge_batch(run0, bk, lane);
    }
    if (cnt1 > 0) {
        unsigned bk = (lane < cnt1) ? ff1[(base1 + lane) & (FIFO_N - 1)] : 0xFFFFFFFFu;
        merge_batch(run1, bk, lane);
    }

    // ---- per row: canonical-fp32 re-rank of 64 survivors + output ----
    // dist32 = fl32( fl32(sq32[n] + sq32[m]) - fl32(2 * dot32) ), components
    // correctly rounded via fp64 accumulation. Ties break by LOWER index.
#pragma unroll
    for (int rr = 0; rr < RPW; ++rr) {
        unsigned runv = (rr == 0) ? run0 : run1;
        int mym = (int)(runv & 0xFFFu);

        double dot64 = 0.0, sqm64 = 0.0, sqn64 = 0.0;
        const float* cp = xb + (size_t)mym * DF;
#pragma unroll
        for (int f = 0; f < DF; ++f) {
            double cv = (double)cp[f];
            double rv = (double)rf[rr][f];
            dot64 = fma(rv, cv, dot64);
            sqm64 = fma(cv, cv, sqm64);
            sqn64 = fma(rv, rv, sqn64);
        }
        float sqn32  = (float)sqn64;
        float sqm32  = (float)sqm64;
        float dot32  = (float)dot64;
        float dist32 = (sqn32 + sqm32) - 2.0f * dot32;

        unsigned long long key =
            ((unsigned long long)sortable32(dist32) << 32) | (unsigned)mym;

        // full-wave bitonic sort, ascending on (dist32, index) — verified R3
#pragma unroll
        for (int k = 2; k <= 64; k <<= 1) {
#pragma unroll
            for (int j = k >> 1; j > 0; j >>= 1) {
                unsigned long long ok = __shfl_xor(key, j);
                bool up       = ((lane & k) == 0);
                bool lower    = ((lane & j) == 0);
                bool takeMin  = (lower == up);
                bool mineLess = (key < ok);
                if (takeMin != mineLess) key = ok;
            }
        }
        mym = (int)(key & 0xFFFFFFFFull);
        // lane k (k<16) now holds the rank-k neighbor index

        const int nn = n0 + rr;
        float wsum = 0.f;
#pragma unroll
        for (int k = 0; k < KNN; ++k) {
            int mk = __shfl(mym, k);                       // uniform
            float v = 0.f;
            if (lane < DF) v = xb[(size_t)mk * DF + lane]; // coalesced gather
            wsum = fmaf(v, w1n[lane & 7][k], wsum);        // lane = d*8+c
        }
        float ov = 0.f;
        const int d_ = lane >> 4, o_ = lane & 15;
#pragma unroll
        for (int c = 0; c < CC; ++c) {
            float wv = __shfl(wsum, d_ * CC + c);
            ov = fmaf(wv, w2n[c][o_], ov);
        }
        out[(size_t)(b * NPTS + nn) * (DD * CO) + lane] = ov;
    }
}

extern "C" void kernel_launch(void* const* d_in, const int* in_sizes, int n_in,
                              void* d_out, int out_size, void* d_ws, size_t ws_size,
                              hipStream_t stream) {
    const float* x  = (const float*)d_in[0];
    const float* w1 = (const float*)d_in[1];
    const float* w2 = (const float*)d_in[2];
    float* out = (float*)d_out;

    wfm_kernel<<<NB * (NPTS / RPB), 256, 0, stream>>>(x, w1, w2, out);
}